// Round 5
// baseline (125.856 us; speedup 1.0000x reference)
//
#include <hip/hip_runtime.h>
#include <hip/hip_bf16.h>
#include <stdint.h>

#define UNITS 1024
#define IDIM  512
#define BATCH 2048
#define KTOT  1536   // UNITS + IDIM
#define NGATE 4096   // 4*UNITS
#define BK    64
#define NITER (KTOT / BK)   // 24

typedef short bf16x8 __attribute__((ext_vector_type(8)));   // 8 bf16 = 4 VGPRs
typedef float f32x4  __attribute__((ext_vector_type(4)));

#define AS3(p) ((__attribute__((address_space(3))) void*)(p))
#define AS1(p) ((const __attribute__((address_space(1))) void*)(p))

union P8 { bf16x8 v; __hip_bfloat16 e[8]; };

// ---------------------------------------------------------------------------
// prep: blocks [0,1536) cast-concat A = bf16(concat[h,x]); blocks [1536,4608)
// transpose W fp32 [1536][4096] -> Wt bf16 [4096][1536] (k-contiguous rows).
// ~56 MB HBM traffic => ~10-12 us, near its roofline.
// ---------------------------------------------------------------------------
#define NBLK_A 1536
#define NBLK_T 3072

__global__ __launch_bounds__(256) void prep(
    const float* __restrict__ x, const float* __restrict__ h,
    const float* __restrict__ W,
    __hip_bfloat16* __restrict__ A, __hip_bfloat16* __restrict__ Wt) {
  __shared__ float tile[32][65];
  const int tid = threadIdx.x;
  if (blockIdx.x < NBLK_A) {
    const int id = blockIdx.x * 256 + tid;
    const int r = id / (KTOT / 8);
    const int k = (id % (KTOT / 8)) * 8;
    const float* src = (k < UNITS) ? h + (size_t)r * UNITS + k
                                   : x + (size_t)r * IDIM + (k - UNITS);
    const float4 v0 = ((const float4*)src)[0];
    const float4 v1 = ((const float4*)src)[1];
    P8 o;
    o.e[0] = __float2bfloat16(v0.x); o.e[1] = __float2bfloat16(v0.y);
    o.e[2] = __float2bfloat16(v0.z); o.e[3] = __float2bfloat16(v0.w);
    o.e[4] = __float2bfloat16(v1.x); o.e[5] = __float2bfloat16(v1.y);
    o.e[6] = __float2bfloat16(v1.z); o.e[7] = __float2bfloat16(v1.w);
    *(bf16x8*)(A + (size_t)r * KTOT + k) = o.v;
  } else {
    const int b  = blockIdx.x - NBLK_A;   // 0..3071
    const int kb = b >> 7;                // 0..23
    const int nb = b & 127;               // 0..127
    const int k0 = kb * 64, n0 = nb * 32;
    const int n4 = (tid & 7) * 4;
    const int kk = tid >> 3;              // 0..31
#pragma unroll
    for (int rr = 0; rr < 64; rr += 32) {
      const float4 v = *(const float4*)(W + (size_t)(k0 + kk + rr) * NGATE + n0 + n4);
      tile[n4 + 0][kk + rr] = v.x; tile[n4 + 1][kk + rr] = v.y;
      tile[n4 + 2][kk + rr] = v.z; tile[n4 + 3][kk + rr] = v.w;
    }
    __syncthreads();
    const int n  = tid >> 3;
    const int k8 = (tid & 7) * 8;
    P8 o;
#pragma unroll
    for (int j = 0; j < 8; ++j) o.e[j] = __float2bfloat16(tile[n][k8 + j]);
    *(bf16x8*)(Wt + (size_t)(n0 + n) * KTOT + k0 + k8) = o.v;
  }
}

// ---------------------------------------------------------------------------
// GEMM + fused LSTM. Grid 512, __launch_bounds__(256,3) -> 3 blocks/CU
// (12 waves/CU, the m97 occupancy that hides barrier drains).
// Block tile 128 rows x 128 vcols (32 units x 4 gates); 4 waves tile 2x2,
// wave = 64 rows x 64 vcols, acc[4][4] (64 VGPR) -- best FLOP/ds_read ratio.
// All 4 gates in-lane -> register-local LSTM epilogue.
//
// LDS 48 KB/block: A double-buffer 2x16 KB @0, B single buffer 16 KB @32768.
// Per iter: pre-read this iter's 8 B-frags LDS->VGPR (breg), barrier1
// (cheap: no vm outstanding -- prior prefetch drained at barrier2), then
// prefetch iter+1 (A -> other A-buf, B -> B-buf IN PLACE, safe because every
// wave holds B in registers), compute (a-frags from A[cur] + breg MFMAs),
// barrier2 (vmcnt drain lands AFTER compute; other 2 blocks cover the stall).
// 16B chunks XOR-swizzled chunk(row,k8)=row*8+(k8^(row&7)) -> 2 lanes/bank
// (free, m136; measured 0 conflicts R1-R3).
// XCD: XCD = bi%8 = ub%8 -> 4 co-XCD blocks share each 1.6 MB Wt slice in L2.
// ---------------------------------------------------------------------------
__global__ __launch_bounds__(256, 3) void lstm_gemm(
    const __hip_bfloat16* __restrict__ A,
    const __hip_bfloat16* __restrict__ Wt,
    const float* __restrict__ c_tm1,
    float* __restrict__ out) {
  __shared__ __attribute__((aligned(128))) char lds[3 * 16384];  // A0 A1 B

  const int tid  = threadIdx.x;
  const int w    = tid >> 6;     // wave 0..3 (uniform)
  const int lane = tid & 63;
  const int quad = lane >> 4;
  const int m16  = lane & 15;
  const int wr   = w >> 1;       // row half (0,1)
  const int wu   = w & 1;        // unit half (0,1)

  const int mb = blockIdx.x >> 5;   // 0..15
  const int ub = blockIdx.x & 31;   // 0..31  (XCD = ub % 8)
  const int m0 = mb * 128;
  const int u0 = ub * 32;

  // A staging: 1024 chunks / 256 thr = 4 per thread; B likewise.
  const __hip_bfloat16* aptr[4];
  const __hip_bfloat16* bptr[4];
  int adst[4], bdst[4];
#pragma unroll
  for (int s = 0; s < 4; ++s) {
    const int q   = s * 4 + w;            // wave-uniform 0..15
    const int ci  = q * 64 + lane;        // chunk 0..1023
    const int row = ci >> 3;              // 0..127
    const int k8  = (ci & 7) ^ (row & 7); // source-side swizzle
    aptr[s] = A + (size_t)(m0 + row) * KTOT + k8 * 8;
    adst[s] = q * 1024;
    const int wrow = ((row >> 5) << 10) + u0 + (row & 31);  // vcol -> Wt row
    bptr[s] = Wt + (size_t)wrow * KTOT + k8 * 8;
    bdst[s] = 32768 + q * 1024;
  }

  f32x4 acc[4][4];
#pragma unroll
  for (int i = 0; i < 4; ++i)
#pragma unroll
    for (int g = 0; g < 4; ++g) {
      f32x4 z = {0.f, 0.f, 0.f, 0.f};
      acc[i][g] = z;
    }

  // prologue: stage iter 0 (A -> buf0, B -> B-buf)
#pragma unroll
  for (int s = 0; s < 4; ++s) {
    __builtin_amdgcn_global_load_lds(AS1(aptr[s]), AS3(lds + adst[s]), 16, 0, 0);
    __builtin_amdgcn_global_load_lds(AS1(bptr[s]), AS3(lds + bdst[s]), 16, 0, 0);
  }
  __syncthreads();

  for (int it = 0; it < NITER; ++it) {
    const int cur = it & 1;
    const int nxt = cur ^ 1;

    // pre-read this iter's B fragments into registers
    bf16x8 breg[4][2];
#pragma unroll
    for (int g = 0; g < 4; ++g)
#pragma unroll
      for (int t = 0; t < 2; ++t) {
        const int vr   = g * 32 + wu * 16 + m16;
        const int slot = (t * 4 + quad) ^ (vr & 7);
        breg[g][t] = *(const bf16x8*)(lds + 32768 + (vr * 8 + slot) * 16);
      }
    __syncthreads();   // barrier1: all waves hold B regs; B-buf may be overwritten

    // prefetch iter it+1: A -> A[nxt], B -> B-buf in place
    if (it < NITER - 1) {
      const int koff = (it + 1) * BK;
#pragma unroll
      for (int s = 0; s < 4; ++s) {
        __builtin_amdgcn_global_load_lds(AS1(aptr[s] + koff),
                                         AS3(lds + nxt * 16384 + adst[s]), 16, 0, 0);
        __builtin_amdgcn_global_load_lds(AS1(bptr[s] + koff),
                                         AS3(lds + bdst[s]), 16, 0, 0);
      }
    }

    // compute iter `it`: a-frags from A[cur], B from registers
    const char* abuf = lds + cur * 16384;
#pragma unroll
    for (int t = 0; t < 2; ++t) {
      bf16x8 a[4];
#pragma unroll
      for (int i = 0; i < 4; ++i) {
        const int row  = wr * 64 + i * 16 + m16;
        const int slot = (t * 4 + quad) ^ (row & 7);
        a[i] = *(const bf16x8*)(abuf + (row * 8 + slot) * 16);
      }
#pragma unroll
      for (int g = 0; g < 4; ++g)
#pragma unroll
        for (int i = 0; i < 4; ++i)
          acc[i][g] = __builtin_amdgcn_mfma_f32_16x16x32_bf16(a[i], breg[g][t],
                                                              acc[i][g], 0, 0, 0);
    }
    __syncthreads();   // barrier2: drains prefetch (vmcnt) after compute
  }

  // fused LSTM epilogue -- all 4 gates in-lane
  const int u = u0 + wu * 16 + m16;
#pragma unroll
  for (int i = 0; i < 4; ++i)
#pragma unroll
    for (int reg = 0; reg < 4; ++reg) {
      const int r = m0 + wr * 64 + i * 16 + quad * 4 + reg;
      const float z0 = acc[i][0][reg];   // gate i
      const float z1 = acc[i][1][reg];   // gate f
      const float z2 = acc[i][2][reg];   // c_tilde
      const float z3 = acc[i][3][reg];   // gate o
      const float ig = 1.f / (1.f + __expf(-z0));
      const float fg = 1.f / (1.f + __expf(-z1));
      const float ct = 1.f - 2.f / (__expf(2.f * z2) + 1.f);   // tanh, inf-safe
      const float og = 1.f / (1.f + __expf(-z3));
      const float cc = fg * c_tm1[(size_t)r * UNITS + u] + ig * ct;
      const float hh = og * (1.f - 2.f / (__expf(2.f * cc) + 1.f));
      out[(size_t)r * UNITS + u] = hh;
      out[(size_t)BATCH * UNITS + (size_t)r * UNITS + u] = cc;
    }
}

// ---------------------------------------------------------------------------
// Fallback (only if d_ws too small): naive fp32, correct but slow.
// ---------------------------------------------------------------------------
__global__ __launch_bounds__(256) void lstm_naive(
    const float* __restrict__ x, const float* __restrict__ h,
    const float* __restrict__ c_tm1, const float* __restrict__ W,
    float* __restrict__ out) {
  int idx = blockIdx.x * 256 + threadIdx.x;
  int r = idx / UNITS;
  int u = idx % UNITS;
  float z[4] = {0.f, 0.f, 0.f, 0.f};
  for (int k = 0; k < KTOT; ++k) {
    float a = (k < UNITS) ? h[(size_t)r * UNITS + k] : x[(size_t)r * IDIM + k - UNITS];
#pragma unroll
    for (int g = 0; g < 4; ++g)
      z[g] += a * W[(size_t)k * NGATE + g * UNITS + u];
  }
  float ig = 1.f / (1.f + __expf(-z[0]));
  float fg = 1.f / (1.f + __expf(-z[1]));
  float ct = 1.f - 2.f / (__expf(2.f * z[2]) + 1.f);
  float og = 1.f / (1.f + __expf(-z[3]));
  float cc = fg * c_tm1[(size_t)r * UNITS + u] + ig * ct;
  float hh = og * (1.f - 2.f / (__expf(2.f * cc) + 1.f));
  out[(size_t)r * UNITS + u] = hh;
  out[(size_t)BATCH * UNITS + (size_t)r * UNITS + u] = cc;
}

extern "C" void kernel_launch(void* const* d_in, const int* in_sizes, int n_in,
                              void* d_out, int out_size, void* d_ws, size_t ws_size,
                              hipStream_t stream) {
  const float* x = (const float*)d_in[0];   // [2048][512]
  const float* h = (const float*)d_in[1];   // [2048][1024]
  const float* c = (const float*)d_in[2];   // [2048][1024]
  const float* W = (const float*)d_in[3];   // [1536][4096]
  float* out = (float*)d_out;               // h then c, 2 x [2048][1024]

  const size_t needA  = (size_t)BATCH * KTOT * sizeof(__hip_bfloat16);  // 6.29 MB
  const size_t needWt = (size_t)NGATE * KTOT * sizeof(__hip_bfloat16);  // 12.58 MB
  if (ws_size < needA + needWt) {
    hipLaunchKernelGGL(lstm_naive, dim3((BATCH * UNITS) / 256), dim3(256), 0, stream,
                       x, h, c, W, out);
    return;
  }

  __hip_bfloat16* A  = (__hip_bfloat16*)d_ws;
  __hip_bfloat16* Wt = (__hip_bfloat16*)((char*)d_ws + needA);

  hipLaunchKernelGGL(prep, dim3(NBLK_A + NBLK_T), dim3(256), 0, stream, x, h, W, A, Wt);
  hipLaunchKernelGGL(lstm_gemm, dim3(512), dim3(256), 0, stream, A, Wt, c, out);
}